// Round 1
// 1772.164 us; speedup vs baseline: 3.0266x; 3.0266x over previous
//
#include <hip/hip_runtime.h>
#include <hip/hip_bf16.h>

typedef __hip_bfloat16 bf16;
typedef __attribute__((ext_vector_type(8))) short short8;   // 8 bf16 (4 VGPRs)
typedef __attribute__((ext_vector_type(4))) float f32x4;

#define NA 100000
#define NT 300000
#define NG 2000
#define EPT 600000
#define ETG 400000

__device__ __forceinline__ float toF(bf16 x) { return __bfloat162float(x); }

// order-preserving encode of f32 into u32 for atomicMax-based segment max
__device__ __forceinline__ unsigned encf(float f) {
    unsigned u = __float_as_uint(f);
    return (u & 0x80000000u) ? ~u : (u | 0x80000000u);
}
__device__ __forceinline__ float decf(unsigned e) {
    return __uint_as_float((e & 0x80000000u) ? (e ^ 0x80000000u) : ~e);
}

__global__ void fill_u32(unsigned* __restrict__ p, unsigned v, long n) {
    long i = (long)blockIdx.x * 256 + threadIdx.x;
    if (i < n) p[i] = v;
}

// ---------------------------------------------------------------------------
// cvtW: convert a 64x256 f32 weight slice to bf16 in MFMA B-fragment order.
// Element order: idx = (((ks*16+nt)*4 + kb)*16 + c)*8 + j
//   holds W[(ks*32 + kb*8 + j)*256 + nt*16 + c]
// so that in the GEMM, lane l of frag (ks,nt) reads 16 contiguous bytes at
// short8 index ((ks*16+nt)*64 + (l>>4)*16 + (l&15)). 2048 threads.
// ---------------------------------------------------------------------------
__global__ __launch_bounds__(256) void cvtW(
    const float* __restrict__ W, short* __restrict__ Bf)
{
    int t = blockIdx.x * 256 + threadIdx.x;
    if (t >= 2048) return;
    int c = t & 15, kb = (t >> 4) & 3, nt = (t >> 6) & 15, ks = t >> 10;
    int k0 = ks * 32 + kb * 8, n = nt * 16 + c;
    short8 o;
#pragma unroll
    for (int j = 0; j < 8; ++j) {
        bf16 v = __float2bfloat16(W[(size_t)(k0 + j) * 256 + n]);
        o[j] = (short)__builtin_bit_cast(unsigned short, v);
    }
    *((short8*)Bf + t) = o;
}

// ---------------------------------------------------------------------------
// tform: C[M x 256] = A[M x 64] (bf16) @ B (bf16, fragment-ordered) + bias.
// 4 waves/block, each wave computes a 16x256 strip via mfma_f32_16x16x32_bf16.
// A frags straight from global (row = 128 B = 1 cache line, fully consumed).
// D layout: col = lane&15, row = (lane>>4)*4 + reg  [verified mapping].
// ---------------------------------------------------------------------------
__global__ __launch_bounds__(256) void tform(
    const bf16* __restrict__ A, const short* __restrict__ Bf,
    const float* __restrict__ bias, bf16* __restrict__ C, int M)
{
    int wv = threadIdx.x >> 6, lane = threadIdx.x & 63;
    int lrow = lane & 15, kb = lane >> 4;
    int base = blockIdx.x * 64 + wv * 16;

    int arow = base + lrow; if (arow >= M) arow = M - 1;   // clamp, stores guarded
    const short* Ap = (const short*)A + (size_t)arow * 64 + kb * 8;
    short8 a0 = *(const short8*)Ap;          // k = kb*8 + j
    short8 a1 = *(const short8*)(Ap + 32);   // k = 32 + kb*8 + j

    const short8* Bl = (const short8*)Bf + kb * 16 + lrow;

    f32x4 acc[16];
#pragma unroll
    for (int nt = 0; nt < 16; ++nt) {
        float bv = bias[nt * 16 + lrow];
        f32x4 bvv = {bv, bv, bv, bv};
        acc[nt] = bvv;
    }
#pragma unroll
    for (int nt = 0; nt < 16; ++nt) {
        short8 b0 = Bl[nt * 64];
        short8 b1 = Bl[(16 + nt) * 64];
        acc[nt] = __builtin_amdgcn_mfma_f32_16x16x32_bf16(a0, b0, acc[nt], 0, 0, 0);
        acc[nt] = __builtin_amdgcn_mfma_f32_16x16x32_bf16(a1, b1, acc[nt], 0, 0, 0);
    }
    int r0 = base + kb * 4;
#pragma unroll
    for (int nt = 0; nt < 16; ++nt) {
#pragma unroll
        for (int r = 0; r < 4; ++r) {
            int row = r0 + r;
            if (row < M)
                C[(size_t)row * 256 + nt * 16 + lrow] = __float2bfloat16(acc[nt][r]);
        }
    }
}

// ---------------------------------------------------------------------------
// ngemm_c4: f32 GEMM, one thread per 4 output cols, K unrolled by 4,
// float4 loads everywhere. Full f32 accumulate (no precision change).
// Used for encoders (bf16 out) and the final linear layers (f32 out).
// ---------------------------------------------------------------------------
template <bool OBF>
__global__ __launch_bounds__(256) void ngemm_c4(
    const float* __restrict__ A, const float* __restrict__ B,
    const float* __restrict__ bias, void* __restrict__ C,
    int M, int N, int K)
{
    long i = (long)blockIdx.x * 256 + threadIdx.x;
    int nq = N >> 2;
    if (i >= (long)M * nq) return;
    int n = (int)(i / nq);
    int c4 = (int)(i - (long)n * nq) << 2;
    const float* Ap = A + (size_t)n * K;
    f32x4 acc = *(const f32x4*)(bias + c4);
    for (int k = 0; k < K; k += 4) {
        f32x4 a = *(const f32x4*)(Ap + k);
#pragma unroll
        for (int kk = 0; kk < 4; ++kk) {
            f32x4 b = *(const f32x4*)(B + (size_t)(k + kk) * N + c4);
            acc += a[kk] * b;
        }
    }
    if (OBF) {
        ushort4 o;
        o.x = __builtin_bit_cast(unsigned short, __float2bfloat16(acc[0]));
        o.y = __builtin_bit_cast(unsigned short, __float2bfloat16(acc[1]));
        o.z = __builtin_bit_cast(unsigned short, __float2bfloat16(acc[2]));
        o.w = __builtin_bit_cast(unsigned short, __float2bfloat16(acc[3]));
        *(ushort4*)((bf16*)C + (size_t)n * N + c4) = o;
    } else {
        *(f32x4*)((float*)C + (size_t)n * N + c4) = acc;
    }
}

// ---------------------------------------------------------------------------
// E1: one thread per (edge, head): s = sum_c leakyrelu(gl+gr)*att; atomicMax.
// ---------------------------------------------------------------------------
__global__ __launch_bounds__(256) void e1_logits(
    const bf16* __restrict__ gl, const bf16* __restrict__ gr,
    const int* __restrict__ src, const int* __restrict__ dst,
    const float* __restrict__ att, float* __restrict__ s,
    unsigned* __restrict__ menc, int E)
{
    long i = (long)blockIdx.x * 256 + threadIdx.x;
    if (i >= (long)E * 4) return;
    int e = (int)(i >> 2), h = (int)(i & 3);
    int se = src[e], de = dst[e];
    const bf16* glp = gl + (size_t)se * 256 + h * 64;
    const bf16* grp = gr + (size_t)de * 256 + h * 64;
    const float* ap = att + h * 64;
    float acc = 0.f;
    for (int c = 0; c < 64; ++c) {
        float v = toF(glp[c]) + toF(grp[c]);
        v = (v > 0.f) ? v : 0.2f * v;
        acc += v * ap[c];
    }
    s[i] = acc;
    atomicMax(&menc[de * 4 + h], encf(acc));
}

// ---------------------------------------------------------------------------
// E2: one thread per (edge, head): ex = exp(s - m[dst]); den += ex.
// ---------------------------------------------------------------------------
__global__ __launch_bounds__(256) void e2_softmax(
    const int* __restrict__ dst, float* __restrict__ s,
    const unsigned* __restrict__ menc, float* __restrict__ den, int E)
{
    long i = (long)blockIdx.x * 256 + threadIdx.x;
    if (i >= (long)E * 4) return;
    int e = (int)(i >> 2), h = (int)(i & 3);
    int de = dst[e];
    float ex = expf(s[i] - decf(menc[de * 4 + h]));
    s[i] = ex;
    atomicAdd(&den[de * 4 + h], ex);
}

// ---------------------------------------------------------------------------
// E3: one thread per (edge, channel): hsum[dst,c] += sum_h alpha_h*gl[src,h,c].
// ---------------------------------------------------------------------------
__global__ __launch_bounds__(256) void e3_aggregate(
    const bf16* __restrict__ gl, const int* __restrict__ src,
    const int* __restrict__ dst, const float* __restrict__ s,
    const float* __restrict__ den, float* __restrict__ hsum, int E)
{
    long i = (long)blockIdx.x * 256 + threadIdx.x;
    if (i >= (long)E * 64) return;
    int e = (int)(i >> 6), c = (int)(i & 63);
    int se = src[e], de = dst[e];
    float acc = 0.f;
    for (int h = 0; h < 4; ++h) {
        float a = s[(size_t)e * 4 + h] / (den[de * 4 + h] + 1e-16f);
        acc += a * toF(gl[(size_t)se * 256 + h * 64 + c]);
    }
    atomicAdd(&hsum[(size_t)de * 64 + c], acc);
}

// ---------------------------------------------------------------------------
// h = elu(0.25*hsum + bias)  (in place, one thread per element)
// ---------------------------------------------------------------------------
__global__ __launch_bounds__(256) void nelu(
    float* __restrict__ hsum, const float* __restrict__ bias, long n)
{
    long i = (long)blockIdx.x * 256 + threadIdx.x;
    if (i >= n) return;
    int c = (int)(i & 63);
    float v = 0.25f * hsum[i] + bias[c];
    hsum[i] = (v > 0.f) ? v : expm1f(v);
}

// ---------------------------------------------------------------------------
// norm[n] = max(sqrt(sum_j y^2), 1e-12)   (one thread per node)
// ---------------------------------------------------------------------------
__global__ __launch_bounds__(256) void nrm(
    const float* __restrict__ y, float* __restrict__ norm, int Nn)
{
    int n = blockIdx.x * 256 + threadIdx.x;
    if (n >= Nn) return;
    const float* yp = y + (size_t)n * 64;
    float ss = 0.f;
    for (int j = 0; j < 64; ++j) ss += yp[j] * yp[j];
    norm[n] = fmaxf(sqrtf(ss), 1e-12f);
}

// ---------------------------------------------------------------------------
// out[n,j] = y[n,j] / norm[n]   (f32 output)
// ---------------------------------------------------------------------------
__global__ __launch_bounds__(256) void nout(
    const float* __restrict__ y, const float* __restrict__ norm,
    float* __restrict__ out, long total)
{
    long i = (long)blockIdx.x * 256 + threadIdx.x;
    if (i >= total) return;
    int n = (int)(i >> 6);
    out[i] = y[i] / norm[n];
}

// ---------------------------------------------------------------------------

static inline unsigned gridFor(long n) { return (unsigned)((n + 255) / 256); }

extern "C" void kernel_launch(void* const* d_in, const int* in_sizes, int n_in,
                              void* d_out, int out_size, void* d_ws, size_t ws_size,
                              hipStream_t stream) {
    const float* x_artist = (const float*)d_in[0];
    const float* x_track  = (const float*)d_in[1];
    const float* x_genre  = (const float*)d_in[2];
    const float* enc_Wa = (const float*)d_in[3];  const float* enc_ba = (const float*)d_in[4];
    const float* enc_Wt = (const float*)d_in[5];  const float* enc_bt = (const float*)d_in[6];
    const float* enc_Wg = (const float*)d_in[7];  const float* enc_bg = (const float*)d_in[8];
    const int* src_pt = (const int*)d_in[9];
    const int* dst_pt = (const int*)d_in[10];
    const int* src_tg = (const int*)d_in[11];
    const int* dst_tg = (const int*)d_in[12];
    // layer l=1 slices (hidden never fed back -> only last layer matters)
    const float* Wl_pt   = (const float*)d_in[13] + 64 * 256;   // (2,64,4,64)
    const float* bl_pt   = (const float*)d_in[14] + 256;        // (2,4,64)
    const float* Wr_pt   = (const float*)d_in[15] + 64 * 256;
    const float* br_pt   = (const float*)d_in[16] + 256;
    const float* att_pt  = (const float*)d_in[17] + 256;        // (2,4,64)
    const float* bias_pt = (const float*)d_in[18] + 64;         // (2,64)
    const float* Wl_tg   = (const float*)d_in[19] + 64 * 256;
    const float* bl_tg   = (const float*)d_in[20] + 256;
    const float* Wr_tg   = (const float*)d_in[21] + 64 * 256;
    const float* br_tg   = (const float*)d_in[22] + 256;
    const float* att_tg  = (const float*)d_in[23] + 256;
    const float* bias_tg = (const float*)d_in[24] + 64;
    const float* lin_track_W = (const float*)d_in[25];
    const float* lin_track_b = (const float*)d_in[26];
    const float* lin_genre_W = (const float*)d_in[27];
    const float* lin_genre_b = (const float*)d_in[28];

    float* out = (float*)d_out;

    // ---- workspace layout (unchanged peak ~277 MB; Bf buffers overlay dead space) ----
    char* p = (char*)d_ws;
    auto take = [&](size_t bytes) { char* q = p; p += (bytes + 255) & ~(size_t)255; return q; };
    bf16* enc_t = (bf16*)take((size_t)NT * 64 * 2);
    bf16* enc_g = (bf16*)take((size_t)NG * 64 * 2);
    bf16* enc_a = (bf16*)take((size_t)NA * 64 * 2);        // tg phase: gr_tg overlays
    char* region = take((size_t)NA * 256 * 2 + (size_t)NT * 256 * 2);   // 204.8 MB
    bf16*  gl_pt  = (bf16*)region;                                      // [0, 51.2 MB)
    bf16*  gr_pt  = (bf16*)(region + (size_t)NA * 256 * 2);             // [51.2, 204.8)
    float* hsum   = (float*)gr_pt;                                      // [51.2, 128.0) after e1
    float* ybuf   = (float*)(region + (size_t)NA * 256 * 2 + (size_t)NT * 64 * 4); // [128.0, 204.8)
    bf16*  gl_tg  = (bf16*)region;                                      // [0, 153.6) tg phase
    float* hsum_g = (float*)(region + (size_t)NT * 256 * 2);            // [153.6, +0.5 MB)
    float* ybuf_g = hsum_g + (size_t)NG * 64;                           // next 0.5 MB
    bf16*  gr_tg  = (bf16*)enc_a;                                       // NG*256 <= enc_a size
    float*    sbuf = (float*)take((size_t)EPT * 4 * 4);
    unsigned* menc = (unsigned*)take((size_t)NT * 4 * 4);
    float*    den  = (float*)take((size_t)NT * 4 * 4);
    float*    norm = (float*)take((size_t)NT * 4);

    // bf16 fragment-ordered weight buffers (32 KB each), overlaid in dead space:
    //  BfA (pt weights) in sbuf: dead before e1 writes sbuf.
    //  BfB (tg weights) in norm: converted after pt-phase nout (norm's last read),
    //  dead before genre-phase nrm writes norm.
    short* BfA = (short*)sbuf;
    short* BfB = (short*)norm;

    dim3 blk(256);

    // ---- pt weight pre-convert ----
    cvtW<<<8, blk, 0, stream>>>(Wl_pt, BfA);
    cvtW<<<8, blk, 0, stream>>>(Wr_pt, BfA + 16384);

    // ---- encoders (f32 x f32 -> bf16, full f32 accumulate) ----
    ngemm_c4<true><<<gridFor((long)NA * 16), blk, 0, stream>>>(x_artist, enc_Wa, enc_ba, enc_a, NA, 64, 64);
    ngemm_c4<true><<<gridFor((long)NT * 16), blk, 0, stream>>>(x_track,  enc_Wt, enc_bt, enc_t, NT, 64, 96);
    ngemm_c4<true><<<gridFor((long)NG * 16), blk, 0, stream>>>(x_genre,  enc_Wg, enc_bg, enc_g, NG, 64, 32);

    // ================= performed: artist -> track =================
    tform<<<(NA + 63) / 64, blk, 0, stream>>>(enc_a, BfA,         bl_pt, gl_pt, NA);
    tform<<<(NT + 63) / 64, blk, 0, stream>>>(enc_t, BfA + 16384, br_pt, gr_pt, NT);

    fill_u32<<<gridFor((long)NT * 4), blk, 0, stream>>>(menc, 0x007FFFFFu, (long)NT * 4);  // enc(-inf)
    fill_u32<<<gridFor((long)NT * 4), blk, 0, stream>>>((unsigned*)den, 0u, (long)NT * 4);

    e1_logits<<<gridFor((long)EPT * 4), blk, 0, stream>>>(gl_pt, gr_pt, src_pt, dst_pt, att_pt, sbuf, menc, EPT);
    e2_softmax<<<gridFor((long)EPT * 4), blk, 0, stream>>>(dst_pt, sbuf, menc, den, EPT);
    // gr_pt dead from here; hsum overlays it
    fill_u32<<<gridFor((long)NT * 64), blk, 0, stream>>>((unsigned*)hsum, 0u, (long)NT * 64);
    e3_aggregate<<<gridFor((long)EPT * 64), blk, 0, stream>>>(gl_pt, src_pt, dst_pt, sbuf, den, hsum, EPT);

    nelu<<<gridFor((long)NT * 64), blk, 0, stream>>>(hsum, bias_pt, (long)NT * 64);
    ngemm_c4<false><<<gridFor((long)NT * 16), blk, 0, stream>>>(hsum, lin_track_W, lin_track_b, ybuf, NT, 64, 64);
    nrm <<<gridFor(NT), blk, 0, stream>>>(ybuf, norm, NT);
    nout<<<gridFor((long)NT * 64), blk, 0, stream>>>(ybuf, norm, out, (long)NT * 64);

    // ================= has_genre: track -> genre =================
    cvtW<<<8, blk, 0, stream>>>(Wl_tg, BfB);
    cvtW<<<8, blk, 0, stream>>>(Wr_tg, BfB + 16384);

    tform<<<(NT + 63) / 64, blk, 0, stream>>>(enc_t, BfB,         bl_tg, gl_tg, NT);
    tform<<<(NG + 63) / 64, blk, 0, stream>>>(enc_g, BfB + 16384, br_tg, gr_tg, NG);

    fill_u32<<<gridFor((long)NG * 4), blk, 0, stream>>>(menc, 0x007FFFFFu, (long)NG * 4);
    fill_u32<<<gridFor((long)NG * 4), blk, 0, stream>>>((unsigned*)den, 0u, (long)NG * 4);
    fill_u32<<<gridFor((long)NG * 64), blk, 0, stream>>>((unsigned*)hsum_g, 0u, (long)NG * 64);

    e1_logits<<<gridFor((long)ETG * 4), blk, 0, stream>>>(gl_tg, gr_tg, src_tg, dst_tg, att_tg, sbuf, menc, ETG);
    e2_softmax<<<gridFor((long)ETG * 4), blk, 0, stream>>>(dst_tg, sbuf, menc, den, ETG);
    e3_aggregate<<<gridFor((long)ETG * 64), blk, 0, stream>>>(gl_tg, src_tg, dst_tg, sbuf, den, hsum_g, ETG);

    nelu<<<gridFor((long)NG * 64), blk, 0, stream>>>(hsum_g, bias_tg, (long)NG * 64);
    ngemm_c4<false><<<gridFor((long)NG * 16), blk, 0, stream>>>(hsum_g, lin_genre_W, lin_genre_b, ybuf_g, NG, 64, 64);
    nrm <<<gridFor(NG), blk, 0, stream>>>(ybuf_g, norm, NG);
    nout<<<gridFor((long)NG * 64), blk, 0, stream>>>(ybuf_g, norm, out + (size_t)NT * 64, (long)NG * 64);
}

// Round 2
// 1220.638 us; speedup vs baseline: 4.3941x; 1.4518x over previous
//
#include <hip/hip_runtime.h>
#include <hip/hip_bf16.h>

typedef __hip_bfloat16 bf16;
typedef __attribute__((ext_vector_type(8))) short short8;   // 8 bf16 (4 VGPRs)
typedef __attribute__((ext_vector_type(4))) float f32x4;

#define NA 100000
#define NT 300000
#define NG 2000
#define EPT 600000
#define ETG 400000

__device__ __forceinline__ float toF(bf16 x) { return __bfloat162float(x); }
__device__ __forceinline__ float b2f(short s) {
    return __uint_as_float(((unsigned)(unsigned short)s) << 16);
}
__device__ __forceinline__ f32x4 b2f4(short4 v) {
    f32x4 r; r[0] = b2f(v.x); r[1] = b2f(v.y); r[2] = b2f(v.z); r[3] = b2f(v.w);
    return r;
}

__global__ void fill_u32(unsigned* __restrict__ p, unsigned v, long n) {
    long i = (long)blockIdx.x * 256 + threadIdx.x;
    if (i < n) p[i] = v;
}

// ---------------------------------------------------------------------------
// cvtW: convert a 64x256 f32 weight slice to bf16 in MFMA B-fragment order.
// idx = (((ks*16+nt)*4 + kb)*16 + c)*8 + j  holds  W[(ks*32+kb*8+j)*256 + nt*16+c]
// ---------------------------------------------------------------------------
__global__ __launch_bounds__(256) void cvtW(
    const float* __restrict__ W, short* __restrict__ Bf)
{
    int t = blockIdx.x * 256 + threadIdx.x;
    if (t >= 2048) return;
    int c = t & 15, kb = (t >> 4) & 3, nt = (t >> 6) & 15, ks = t >> 10;
    int k0 = ks * 32 + kb * 8, n = nt * 16 + c;
    short8 o;
#pragma unroll
    for (int j = 0; j < 8; ++j) {
        bf16 v = __float2bfloat16(W[(size_t)(k0 + j) * 256 + n]);
        o[j] = (short)__builtin_bit_cast(unsigned short, v);
    }
    *((short8*)Bf + t) = o;
}

// ---------------------------------------------------------------------------
// tform: C[M x 256] = A[M x 64] (bf16) @ B (bf16 frag-ordered) + bias, MFMA.
// ---------------------------------------------------------------------------
__global__ __launch_bounds__(256) void tform(
    const bf16* __restrict__ A, const short* __restrict__ Bf,
    const float* __restrict__ bias, bf16* __restrict__ C, int M)
{
    int wv = threadIdx.x >> 6, lane = threadIdx.x & 63;
    int lrow = lane & 15, kb = lane >> 4;
    int base = blockIdx.x * 64 + wv * 16;

    int arow = base + lrow; if (arow >= M) arow = M - 1;
    const short* Ap = (const short*)A + (size_t)arow * 64 + kb * 8;
    short8 a0 = *(const short8*)Ap;
    short8 a1 = *(const short8*)(Ap + 32);

    const short8* Bl = (const short8*)Bf + kb * 16 + lrow;

    f32x4 acc[16];
#pragma unroll
    for (int nt = 0; nt < 16; ++nt) {
        float bv = bias[nt * 16 + lrow];
        f32x4 bvv = {bv, bv, bv, bv};
        acc[nt] = bvv;
    }
#pragma unroll
    for (int nt = 0; nt < 16; ++nt) {
        short8 b0 = Bl[nt * 64];
        short8 b1 = Bl[(16 + nt) * 64];
        acc[nt] = __builtin_amdgcn_mfma_f32_16x16x32_bf16(a0, b0, acc[nt], 0, 0, 0);
        acc[nt] = __builtin_amdgcn_mfma_f32_16x16x32_bf16(a1, b1, acc[nt], 0, 0, 0);
    }
    int r0 = base + kb * 4;
#pragma unroll
    for (int nt = 0; nt < 16; ++nt) {
#pragma unroll
        for (int r = 0; r < 4; ++r) {
            int row = r0 + r;
            if (row < M)
                C[(size_t)row * 256 + nt * 16 + lrow] = __float2bfloat16(acc[nt][r]);
        }
    }
}

// ---------------------------------------------------------------------------
// ngemm_c4: f32 GEMM, thread per 4 cols, K unrolled by 4, float4 loads.
// ---------------------------------------------------------------------------
template <bool OBF>
__global__ __launch_bounds__(256) void ngemm_c4(
    const float* __restrict__ A, const float* __restrict__ B,
    const float* __restrict__ bias, void* __restrict__ C,
    int M, int N, int K)
{
    long i = (long)blockIdx.x * 256 + threadIdx.x;
    int nq = N >> 2;
    if (i >= (long)M * nq) return;
    int n = (int)(i / nq);
    int c4 = (int)(i - (long)n * nq) << 2;
    const float* Ap = A + (size_t)n * K;
    f32x4 acc = *(const f32x4*)(bias + c4);
    for (int k = 0; k < K; k += 4) {
        f32x4 a = *(const f32x4*)(Ap + k);
#pragma unroll
        for (int kk = 0; kk < 4; ++kk) {
            f32x4 b = *(const f32x4*)(B + (size_t)(k + kk) * N + c4);
            acc += a[kk] * b;
        }
    }
    if (OBF) {
        ushort4 o;
        o.x = __builtin_bit_cast(unsigned short, __float2bfloat16(acc[0]));
        o.y = __builtin_bit_cast(unsigned short, __float2bfloat16(acc[1]));
        o.z = __builtin_bit_cast(unsigned short, __float2bfloat16(acc[2]));
        o.w = __builtin_bit_cast(unsigned short, __float2bfloat16(acc[3]));
        *(ushort4*)((bf16*)C + (size_t)n * N + c4) = o;
    } else {
        *(f32x4*)((float*)C + (size_t)n * N + c4) = acc;
    }
}

// ============================ edge sort (CSR by dst) ========================
__global__ __launch_bounds__(256) void histo(
    const int* __restrict__ dst, unsigned* __restrict__ cnt, int E)
{
    int i = blockIdx.x * 256 + threadIdx.x;
    if (i < E) atomicAdd(&cnt[dst[i]], 1u);
}

// two-level exclusive scan; block handles 1024 elems (4/thread)
__global__ __launch_bounds__(256) void scan_a(
    const unsigned* __restrict__ in, unsigned* __restrict__ out,
    unsigned* __restrict__ part, int n)
{
    __shared__ unsigned ts[256];
    int t = threadIdx.x;
    long base = (long)blockIdx.x * 1024 + (long)t * 4;
    unsigned v0 = 0, v1 = 0, v2 = 0, v3 = 0;
    if (base + 0 < n) v0 = in[base + 0];
    if (base + 1 < n) v1 = in[base + 1];
    if (base + 2 < n) v2 = in[base + 2];
    if (base + 3 < n) v3 = in[base + 3];
    unsigned s = v0 + v1 + v2 + v3;
    ts[t] = s;
    __syncthreads();
    unsigned run = s;
    for (int off = 1; off < 256; off <<= 1) {
        unsigned y = (t >= off) ? ts[t - off] : 0u;
        __syncthreads();
        run += y; ts[t] = run;
        __syncthreads();
    }
    unsigned ex = run - s;
    if (base + 0 < n) out[base + 0] = ex;
    if (base + 1 < n) out[base + 1] = ex + v0;
    if (base + 2 < n) out[base + 2] = ex + v0 + v1;
    if (base + 3 < n) out[base + 3] = ex + v0 + v1 + v2;
    if (t == 255) part[blockIdx.x] = run;
}

__global__ __launch_bounds__(256) void scan_c(
    unsigned* __restrict__ rp, const unsigned* __restrict__ part,
    unsigned* __restrict__ cur, int n)
{
    long i = (long)blockIdx.x * 256 + threadIdx.x;
    if (i >= n) return;
    unsigned v = rp[i] + part[i >> 10];
    rp[i] = v;
    if (i < n - 1) cur[i] = v;
}

__global__ __launch_bounds__(256) void scat(
    const int* __restrict__ src, const int* __restrict__ dst,
    unsigned* __restrict__ cur, int* __restrict__ ss, int E)
{
    int i = blockIdx.x * 256 + threadIdx.x;
    if (i < E) {
        unsigned p = atomicAdd(&cur[dst[i]], 1u);
        ss[p] = src[i];
    }
}

// ---------------------------------------------------------------------------
// gat_w: fused GATv2 (track phase). One wave per dst; online softmax in regs;
// epilogue fuses head-mean + bias + elu + 64x64 linear + l2norm + store.
// Lane l holds flat elems 4l..4l+3 (elem = head*64 + ch).
// ---------------------------------------------------------------------------
__global__ __launch_bounds__(256) void gat_w(
    const bf16* __restrict__ gl, const bf16* __restrict__ gr,
    const int* __restrict__ ssrc, const unsigned* __restrict__ rp,
    const float* __restrict__ att, const float* __restrict__ bias,
    const float* __restrict__ linW, const float* __restrict__ linb,
    float* __restrict__ outp, int Nd)
{
    // lin weight, transposed + 16B-block XOR swizzle: block q=c4^(j&15) of row j
    __shared__ float WT[64 * 64];
    __shared__ float hL[4][64];
    for (int t = threadIdx.x; t < 4096; t += 256) {
        int c = t >> 6, j = t & 63;
        WT[j * 64 + (((c >> 2) ^ (j & 15)) << 2) + (c & 3)] = linW[t];
    }
    __syncthreads();

    int wv = threadIdx.x >> 6, lane = threadIdx.x & 63;
    f32x4 at = ((const f32x4*)att)[lane];
    f32x4 bv = ((const f32x4*)bias)[lane & 15];
    float lb = linb[lane];

    int ng = (Nd + 3) >> 2;
    for (int g = blockIdx.x; g < ng; g += gridDim.x) {
        int d = g * 4 + wv;
        if (d >= Nd) continue;
        f32x4 grf = b2f4(((const short4*)gr)[(size_t)d * 64 + lane]);
        unsigned beg = rp[d], end = rp[d + 1];
        float m = -1e30f, den = 0.f;
        f32x4 acc = {0.f, 0.f, 0.f, 0.f};
        for (unsigned e = beg; e < end; ++e) {
            int si = ssrc[e];
            f32x4 glf = b2f4(((const short4*)gl)[(size_t)si * 64 + lane]);
            f32x4 v = glf + grf;
#pragma unroll
            for (int j = 0; j < 4; ++j) v[j] = v[j] > 0.f ? v[j] : 0.2f * v[j];
            float pp = v[0] * at[0] + v[1] * at[1] + v[2] * at[2] + v[3] * at[3];
            pp += __shfl_xor(pp, 1); pp += __shfl_xor(pp, 2);
            pp += __shfl_xor(pp, 4); pp += __shfl_xor(pp, 8);
            float mn = fmaxf(m, pp);
            float fo = __expf(m - mn), w = __expf(pp - mn);
            den = den * fo + w;
            acc = acc * fo + w * glf;
            m = mn;
        }
        float inv = den > 0.f ? 1.f / den : 0.f;
        f32x4 o;
#pragma unroll
        for (int j = 0; j < 4; ++j) {
            float x = acc[j] * inv;
            x += __shfl_xor(x, 16);
            x += __shfl_xor(x, 32);
            float hb = 0.25f * x + bv[j];
            o[j] = hb > 0.f ? hb : expm1f(hb);
        }
        if (lane < 16) ((f32x4*)hL[wv])[lane] = o;   // h: 64 f32, replicated source
        // y_j = linb[j] + sum_c h_c * W[c][j]   (j = lane)
        float y = lb;
#pragma unroll
        for (int c4 = 0; c4 < 16; ++c4) {
            f32x4 hv = *((const f32x4*)&hL[wv][c4 * 4]);            // broadcast
            f32x4 wt = *((const f32x4*)&WT[lane * 64 + ((c4 ^ (lane & 15)) << 2)]);
            y = fmaf(hv[0], wt[0], y); y = fmaf(hv[1], wt[1], y);
            y = fmaf(hv[2], wt[2], y); y = fmaf(hv[3], wt[3], y);
        }
        float ss = y * y;
        ss += __shfl_xor(ss, 1);  ss += __shfl_xor(ss, 2);  ss += __shfl_xor(ss, 4);
        ss += __shfl_xor(ss, 8);  ss += __shfl_xor(ss, 16); ss += __shfl_xor(ss, 32);
        float nv = fmaxf(sqrtf(ss), 1e-12f);
        outp[(size_t)d * 64 + lane] = y / nv;
    }
}

// ---------------------------------------------------------------------------
// gat_b: fused GATv2 (genre phase). One block (4 waves) per dst; waves split
// edges 4-way; LDS merge of (m, den, acc); writes h = elu(mean + bias).
// ---------------------------------------------------------------------------
__global__ __launch_bounds__(256) void gat_b(
    const bf16* __restrict__ gl, const bf16* __restrict__ gr,
    const int* __restrict__ ssrc, const unsigned* __restrict__ rp,
    const float* __restrict__ att, const float* __restrict__ bias,
    float* __restrict__ hout, int Nd)
{
    __shared__ float accL[4][256];
    __shared__ float mL[4][4], dL[4][4];
    int wv = threadIdx.x >> 6, lane = threadIdx.x & 63;
    int d = blockIdx.x;
    f32x4 at = ((const f32x4*)att)[lane];
    f32x4 grf = b2f4(((const short4*)gr)[(size_t)d * 64 + lane]);
    unsigned beg = rp[d], end = rp[d + 1];
    float m = -1e30f, den = 0.f;
    f32x4 acc = {0.f, 0.f, 0.f, 0.f};
    for (unsigned e = beg + wv; e < end; e += 4) {
        int si = ssrc[e];
        f32x4 glf = b2f4(((const short4*)gl)[(size_t)si * 64 + lane]);
        f32x4 v = glf + grf;
#pragma unroll
        for (int j = 0; j < 4; ++j) v[j] = v[j] > 0.f ? v[j] : 0.2f * v[j];
        float pp = v[0] * at[0] + v[1] * at[1] + v[2] * at[2] + v[3] * at[3];
        pp += __shfl_xor(pp, 1); pp += __shfl_xor(pp, 2);
        pp += __shfl_xor(pp, 4); pp += __shfl_xor(pp, 8);
        float mn = fmaxf(m, pp);
        float fo = __expf(m - mn), w = __expf(pp - mn);
        den = den * fo + w;
        acc = acc * fo + w * glf;
        m = mn;
    }
    ((f32x4*)accL[wv])[lane] = acc;
    if (!(lane & 15)) { mL[wv][lane >> 4] = m; dL[wv][lane >> 4] = den; }
    __syncthreads();
    int h = lane >> 4;
    float M = fmaxf(fmaxf(mL[0][h], mL[1][h]), fmaxf(mL[2][h], mL[3][h]));
    float D = 0.f;
    f32x4 A = {0.f, 0.f, 0.f, 0.f};
#pragma unroll
    for (int w2 = 0; w2 < 4; ++w2) {
        float fo = __expf(mL[w2][h] - M);
        D += dL[w2][h] * fo;
        f32x4 aw = ((const f32x4*)accL[w2])[lane];
        A += fo * aw;
    }
    float inv = D > 0.f ? 1.f / D : 0.f;
    f32x4 bvv = ((const f32x4*)bias)[lane & 15];
    f32x4 o;
#pragma unroll
    for (int j = 0; j < 4; ++j) {
        float x = A[j] * inv;
        x += __shfl_xor(x, 16);
        x += __shfl_xor(x, 32);
        float hb = 0.25f * x + bvv[j];
        o[j] = hb > 0.f ? hb : expm1f(hb);
    }
    if (lane < 16) ((f32x4*)hout)[(size_t)d * 16 + lane] = o;
}

// ---------------------------------------------------------------------------
__global__ __launch_bounds__(256) void nrm(
    const float* __restrict__ y, float* __restrict__ norm, int Nn)
{
    int n = blockIdx.x * 256 + threadIdx.x;
    if (n >= Nn) return;
    const float* yp = y + (size_t)n * 64;
    float ss = 0.f;
    for (int j = 0; j < 64; ++j) ss += yp[j] * yp[j];
    norm[n] = fmaxf(sqrtf(ss), 1e-12f);
}

__global__ __launch_bounds__(256) void nout(
    const float* __restrict__ y, const float* __restrict__ norm,
    float* __restrict__ out, long total)
{
    long i = (long)blockIdx.x * 256 + threadIdx.x;
    if (i >= total) return;
    int n = (int)(i >> 6);
    out[i] = y[i] / norm[n];
}

// ---------------------------------------------------------------------------

static inline unsigned gridFor(long n) { return (unsigned)((n + 255) / 256); }

extern "C" void kernel_launch(void* const* d_in, const int* in_sizes, int n_in,
                              void* d_out, int out_size, void* d_ws, size_t ws_size,
                              hipStream_t stream) {
    const float* x_artist = (const float*)d_in[0];
    const float* x_track  = (const float*)d_in[1];
    const float* x_genre  = (const float*)d_in[2];
    const float* enc_Wa = (const float*)d_in[3];  const float* enc_ba = (const float*)d_in[4];
    const float* enc_Wt = (const float*)d_in[5];  const float* enc_bt = (const float*)d_in[6];
    const float* enc_Wg = (const float*)d_in[7];  const float* enc_bg = (const float*)d_in[8];
    const int* src_pt = (const int*)d_in[9];
    const int* dst_pt = (const int*)d_in[10];
    const int* src_tg = (const int*)d_in[11];
    const int* dst_tg = (const int*)d_in[12];
    // layer l=1 slices (hidden never fed back -> only last layer matters)
    const float* Wl_pt   = (const float*)d_in[13] + 64 * 256;
    const float* bl_pt   = (const float*)d_in[14] + 256;
    const float* Wr_pt   = (const float*)d_in[15] + 64 * 256;
    const float* br_pt   = (const float*)d_in[16] + 256;
    const float* att_pt  = (const float*)d_in[17] + 256;
    const float* bias_pt = (const float*)d_in[18] + 64;
    const float* Wl_tg   = (const float*)d_in[19] + 64 * 256;
    const float* bl_tg   = (const float*)d_in[20] + 256;
    const float* Wr_tg   = (const float*)d_in[21] + 64 * 256;
    const float* br_tg   = (const float*)d_in[22] + 256;
    const float* att_tg  = (const float*)d_in[23] + 256;
    const float* bias_tg = (const float*)d_in[24] + 64;
    const float* lin_track_W = (const float*)d_in[25];
    const float* lin_track_b = (const float*)d_in[26];
    const float* lin_genre_W = (const float*)d_in[27];
    const float* lin_genre_b = (const float*)d_in[28];

    float* out = (float*)d_out;

    // ---- workspace layout (~264 MB, within previous ~277 MB peak) ----
    char* p = (char*)d_ws;
    auto take = [&](size_t bytes) { char* q = p; p += (bytes + 255) & ~(size_t)255; return q; };
    bf16* enc_t = (bf16*)take((size_t)NT * 64 * 2);
    bf16* enc_g = (bf16*)take((size_t)NG * 64 * 2);
    bf16* enc_a = (bf16*)take((size_t)NA * 64 * 2);        // tg phase: gr_tg overlays
    char* region = take((size_t)NA * 256 * 2 + (size_t)NT * 256 * 2);   // 204.8 MB
    bf16*  gl_pt  = (bf16*)region;                                      // pt: [0, 51.2 MB)
    bf16*  gr_pt  = (bf16*)(region + (size_t)NA * 256 * 2);             // pt: [51.2, 204.8)
    bf16*  gl_tg  = (bf16*)region;                                      // tg: [0, 153.6)
    float* hsum_g = (float*)(region + (size_t)NT * 256 * 2);            // tg: +0.5 MB
    float* ybuf_g = hsum_g + (size_t)NG * 64;
    bf16*  gr_tg  = (bf16*)enc_a;                                       // NG*256 fits
    unsigned* counts = (unsigned*)take((size_t)(NT + 1) * 4);
    unsigned* rowptr = (unsigned*)take((size_t)(NT + 1) * 4);
    unsigned* cursor = (unsigned*)take((size_t)NT * 4);
    unsigned* part   = (unsigned*)take((size_t)2048 * 4);
    int*      ssrc   = (int*)take((size_t)EPT * 4);
    short*    Bf     = (short*)take((size_t)4 * 16384 * 2);
    float*    norm   = (float*)take((size_t)NT * 4);

    short* BfA  = Bf;              // Wl_pt frag
    short* BfA2 = Bf + 16384;      // Wr_pt frag
    short* BfB  = Bf + 32768;      // Wl_tg frag
    short* BfB2 = Bf + 49152;      // Wr_tg frag

    dim3 blk(256);

    // ---- weight converts ----
    cvtW<<<8, blk, 0, stream>>>(Wl_pt, BfA);
    cvtW<<<8, blk, 0, stream>>>(Wr_pt, BfA2);
    cvtW<<<8, blk, 0, stream>>>(Wl_tg, BfB);
    cvtW<<<8, blk, 0, stream>>>(Wr_tg, BfB2);

    // ---- sort pt edges by dst (counting sort -> CSR) ----
    {
        int n = NT + 1;
        unsigned sgrid = (unsigned)((n + 1023) / 1024);
        fill_u32<<<gridFor(n), blk, 0, stream>>>(counts, 0u, n);
        histo<<<gridFor(EPT), blk, 0, stream>>>(dst_pt, counts, EPT);
        scan_a<<<sgrid, blk, 0, stream>>>(counts, rowptr, part, n);
        scan_a<<<1, blk, 0, stream>>>(part, part, part + 1536, (int)sgrid);
        scan_c<<<gridFor(n), blk, 0, stream>>>(rowptr, part, cursor, n);
        scat<<<gridFor(EPT), blk, 0, stream>>>(src_pt, dst_pt, cursor, ssrc, EPT);
    }

    // ---- encoders ----
    ngemm_c4<true><<<gridFor((long)NA * 16), blk, 0, stream>>>(x_artist, enc_Wa, enc_ba, enc_a, NA, 64, 64);
    ngemm_c4<true><<<gridFor((long)NT * 16), blk, 0, stream>>>(x_track,  enc_Wt, enc_bt, enc_t, NT, 64, 96);
    ngemm_c4<true><<<gridFor((long)NG * 16), blk, 0, stream>>>(x_genre,  enc_Wg, enc_bg, enc_g, NG, 64, 32);

    // ================= performed: artist -> track =================
    tform<<<(NA + 63) / 64, blk, 0, stream>>>(enc_a, BfA,  bl_pt, gl_pt, NA);
    tform<<<(NT + 63) / 64, blk, 0, stream>>>(enc_t, BfA2, br_pt, gr_pt, NT);

    gat_w<<<2048, blk, 0, stream>>>(gl_pt, gr_pt, ssrc, rowptr, att_pt, bias_pt,
                                    lin_track_W, lin_track_b, out, NT);

    // ---- sort tg edges by dst ----
    {
        int n = NG + 1;
        unsigned sgrid = (unsigned)((n + 1023) / 1024);
        fill_u32<<<gridFor(n), blk, 0, stream>>>(counts, 0u, n);
        histo<<<gridFor(ETG), blk, 0, stream>>>(dst_tg, counts, ETG);
        scan_a<<<sgrid, blk, 0, stream>>>(counts, rowptr, part, n);
        scan_a<<<1, blk, 0, stream>>>(part, part, part + 1536, (int)sgrid);
        scan_c<<<gridFor(n), blk, 0, stream>>>(rowptr, part, cursor, n);
        scat<<<gridFor(ETG), blk, 0, stream>>>(src_tg, dst_tg, cursor, ssrc, ETG);
    }

    // ================= has_genre: track -> genre =================
    tform<<<(NT + 63) / 64, blk, 0, stream>>>(enc_t, BfB,  bl_tg, gl_tg, NT);
    tform<<<(NG + 63) / 64, blk, 0, stream>>>(enc_g, BfB2, br_tg, gr_tg, NG);

    gat_b<<<NG, blk, 0, stream>>>(gl_tg, gr_tg, ssrc, rowptr, att_tg, bias_tg, hsum_g, NG);

    ngemm_c4<false><<<gridFor((long)NG * 16), blk, 0, stream>>>(hsum_g, lin_genre_W, lin_genre_b, ybuf_g, NG, 64, 64);
    nrm <<<gridFor(NG), blk, 0, stream>>>(ybuf_g, norm, NG);
    nout<<<gridFor((long)NG * 64), blk, 0, stream>>>(ybuf_g, norm, out + (size_t)NT * 64, (long)NG * 64);
}

// Round 3
// 1087.290 us; speedup vs baseline: 4.9331x; 1.1226x over previous
//
#include <hip/hip_runtime.h>
#include <hip/hip_bf16.h>

typedef __hip_bfloat16 bf16;
typedef __attribute__((ext_vector_type(8))) short short8;   // 8 bf16 (4 VGPRs)
typedef __attribute__((ext_vector_type(4))) float f32x4;

#define NA 100000
#define NT 300000
#define NG 2000
#define EPT 600000
#define ETG 400000

// DPP control codes
#define DPP_QX1 0xB1   // quad_perm [1,0,3,2]  (xor 1)
#define DPP_QX2 0x4E   // quad_perm [2,3,0,1]  (xor 2)
#define DPP_RR4 0x124  // row_ror:4
#define DPP_RR8 0x128  // row_ror:8

template <int CTRL>
__device__ __forceinline__ float dppadd(float x) {
    int y = __builtin_amdgcn_update_dpp(0, __float_as_int(x), CTRL, 0xf, 0xf, true);
    return x + __int_as_float(y);
}

__device__ __forceinline__ float b2f(short s) {
    return __uint_as_float(((unsigned)(unsigned short)s) << 16);
}
__device__ __forceinline__ void cvt16(short8 a, short8 b, float* f) {
#pragma unroll
    for (int j = 0; j < 8; ++j) f[j] = b2f(a[j]);
#pragma unroll
    for (int j = 0; j < 8; ++j) f[8 + j] = b2f(b[j]);
}

__global__ void fill_u32(unsigned* __restrict__ p, unsigned v, long n) {
    long i = (long)blockIdx.x * 256 + threadIdx.x;
    if (i < n) p[i] = v;
}

// ---------------------------------------------------------------------------
// cvtW: convert a 64x256 f32 weight slice to bf16 in MFMA B-fragment order.
// idx = (((ks*16+nt)*4 + kb)*16 + c)*8 + j  holds  W[(ks*32+kb*8+j)*256 + nt*16+c]
// ---------------------------------------------------------------------------
__global__ __launch_bounds__(256) void cvtW(
    const float* __restrict__ W, short* __restrict__ Bf)
{
    int t = blockIdx.x * 256 + threadIdx.x;
    if (t >= 2048) return;
    int c = t & 15, kb = (t >> 4) & 3, nt = (t >> 6) & 15, ks = t >> 10;
    int k0 = ks * 32 + kb * 8, n = nt * 16 + c;
    short8 o;
#pragma unroll
    for (int j = 0; j < 8; ++j) {
        bf16 v = __float2bfloat16(W[(size_t)(k0 + j) * 256 + n]);
        o[j] = (short)__builtin_bit_cast(unsigned short, v);
    }
    *((short8*)Bf + t) = o;
}

// ---------------------------------------------------------------------------
// tform: C[M x 256] = A[M x 64] (bf16) @ B (bf16 frag-ordered) + bias, MFMA.
// ---------------------------------------------------------------------------
__global__ __launch_bounds__(256) void tform(
    const bf16* __restrict__ A, const short* __restrict__ Bf,
    const float* __restrict__ bias, bf16* __restrict__ C, int M)
{
    int wv = threadIdx.x >> 6, lane = threadIdx.x & 63;
    int lrow = lane & 15, kb = lane >> 4;
    int base = blockIdx.x * 64 + wv * 16;

    int arow = base + lrow; if (arow >= M) arow = M - 1;
    const short* Ap = (const short*)A + (size_t)arow * 64 + kb * 8;
    short8 a0 = *(const short8*)Ap;
    short8 a1 = *(const short8*)(Ap + 32);

    const short8* Bl = (const short8*)Bf + kb * 16 + lrow;

    f32x4 acc[16];
#pragma unroll
    for (int nt = 0; nt < 16; ++nt) {
        float bv = bias[nt * 16 + lrow];
        f32x4 bvv = {bv, bv, bv, bv};
        acc[nt] = bvv;
    }
#pragma unroll
    for (int nt = 0; nt < 16; ++nt) {
        short8 b0 = Bl[nt * 64];
        short8 b1 = Bl[(16 + nt) * 64];
        acc[nt] = __builtin_amdgcn_mfma_f32_16x16x32_bf16(a0, b0, acc[nt], 0, 0, 0);
        acc[nt] = __builtin_amdgcn_mfma_f32_16x16x32_bf16(a1, b1, acc[nt], 0, 0, 0);
    }
    int r0 = base + kb * 4;
#pragma unroll
    for (int nt = 0; nt < 16; ++nt) {
#pragma unroll
        for (int r = 0; r < 4; ++r) {
            int row = r0 + r;
            if (row < M)
                C[(size_t)row * 256 + nt * 16 + lrow] = __float2bfloat16(acc[nt][r]);
        }
    }
}

// ---------------------------------------------------------------------------
// ngemm_c4: f32 GEMM, thread per 4 cols, K unrolled by 4, float4 loads.
// ---------------------------------------------------------------------------
template <bool OBF>
__global__ __launch_bounds__(256) void ngemm_c4(
    const float* __restrict__ A, const float* __restrict__ B,
    const float* __restrict__ bias, void* __restrict__ C,
    int M, int N, int K)
{
    long i = (long)blockIdx.x * 256 + threadIdx.x;
    int nq = N >> 2;
    if (i >= (long)M * nq) return;
    int n = (int)(i / nq);
    int c4 = (int)(i - (long)n * nq) << 2;
    const float* Ap = A + (size_t)n * K;
    f32x4 acc = *(const f32x4*)(bias + c4);
    for (int k = 0; k < K; k += 4) {
        f32x4 a = *(const f32x4*)(Ap + k);
#pragma unroll
        for (int kk = 0; kk < 4; ++kk) {
            f32x4 b = *(const f32x4*)(B + (size_t)(k + kk) * N + c4);
            acc += a[kk] * b;
        }
    }
    if (OBF) {
        ushort4 o;
        o.x = __builtin_bit_cast(unsigned short, __float2bfloat16(acc[0]));
        o.y = __builtin_bit_cast(unsigned short, __float2bfloat16(acc[1]));
        o.z = __builtin_bit_cast(unsigned short, __float2bfloat16(acc[2]));
        o.w = __builtin_bit_cast(unsigned short, __float2bfloat16(acc[3]));
        *(ushort4*)((bf16*)C + (size_t)n * N + c4) = o;
    } else {
        *(f32x4*)((float*)C + (size_t)n * N + c4) = acc;
    }
}

// ============================ edge sort (CSR by dst) ========================
__global__ __launch_bounds__(256) void histo(
    const int* __restrict__ dst, unsigned* __restrict__ cnt, int E)
{
    int i = blockIdx.x * 256 + threadIdx.x;
    if (i < E) atomicAdd(&cnt[dst[i]], 1u);
}

__global__ __launch_bounds__(256) void scan_a(
    const unsigned* __restrict__ in, unsigned* __restrict__ out,
    unsigned* __restrict__ part, int n)
{
    __shared__ unsigned ts[256];
    int t = threadIdx.x;
    long base = (long)blockIdx.x * 1024 + (long)t * 4;
    unsigned v0 = 0, v1 = 0, v2 = 0, v3 = 0;
    if (base + 0 < n) v0 = in[base + 0];
    if (base + 1 < n) v1 = in[base + 1];
    if (base + 2 < n) v2 = in[base + 2];
    if (base + 3 < n) v3 = in[base + 3];
    unsigned s = v0 + v1 + v2 + v3;
    ts[t] = s;
    __syncthreads();
    unsigned run = s;
    for (int off = 1; off < 256; off <<= 1) {
        unsigned y = (t >= off) ? ts[t - off] : 0u;
        __syncthreads();
        run += y; ts[t] = run;
        __syncthreads();
    }
    unsigned ex = run - s;
    if (base + 0 < n) out[base + 0] = ex;
    if (base + 1 < n) out[base + 1] = ex + v0;
    if (base + 2 < n) out[base + 2] = ex + v0 + v1;
    if (base + 3 < n) out[base + 3] = ex + v0 + v1 + v2;
    if (t == 255) part[blockIdx.x] = run;
}

__global__ __launch_bounds__(256) void scan_c(
    unsigned* __restrict__ rp, const unsigned* __restrict__ part,
    unsigned* __restrict__ cur, int n)
{
    long i = (long)blockIdx.x * 256 + threadIdx.x;
    if (i >= n) return;
    unsigned v = rp[i] + part[i >> 10];
    rp[i] = v;
    if (i < n - 1) cur[i] = v;
}

__global__ __launch_bounds__(256) void scat(
    const int* __restrict__ src, const int* __restrict__ dst,
    unsigned* __restrict__ cur, int* __restrict__ ss, int E)
{
    int i = blockIdx.x * 256 + threadIdx.x;
    if (i < E) {
        unsigned p = atomicAdd(&cur[dst[i]], 1u);
        ss[p] = src[i];
    }
}

// ---------------------------------------------------------------------------
// gat_w: fused GATv2 (track phase), 16-lane-group per dst (4 dst per wave).
// Lane g (=tid&15): head h=g&3, chunk q=g>>2, elems [h*64+q*16 .. +15].
// No running max (|logit| << 1 -> exp(s) exact-safe; softmax shift-invariant).
// Attention dot: in-lane 16 FMA + DPP row_ror:4/8 (stride-4 lane class = head).
// Head mean: DPP quad_perm (quad = same chunk, 4 heads).
// Epilogue fuses bias+elu+64x64 linear+l2norm+store; h broadcast via LDS
// (same-wave, no barrier needed).
// ---------------------------------------------------------------------------
__global__ __launch_bounds__(256) void gat_w(
    const bf16* __restrict__ gl, const bf16* __restrict__ gr,
    const int* __restrict__ ssrc, const unsigned* __restrict__ rp,
    const float* __restrict__ att, const float* __restrict__ bias,
    const float* __restrict__ linW, const float* __restrict__ linb,
    float* __restrict__ outp, int Nd)
{
    __shared__ float WL[4096];        // linW [c][j] row-major
    __shared__ float bL[64];
    __shared__ float hL[16][68];      // per-group h, padded
    for (int t = threadIdx.x; t < 4096; t += 256) WL[t] = linW[t];
    if (threadIdx.x < 64) bL[threadIdx.x] = linb ? bias[threadIdx.x] : 0.f;
    __syncthreads();

    int grp = threadIdx.x >> 4, g = threadIdx.x & 15;
    int h = g & 3, q = g >> 2;
    int eoff = h * 64 + q * 16;

    float at[16];
#pragma unroll
    for (int j = 0; j < 16; ++j) at[j] = att[eoff + j];
    f32x4 lbv = *(const f32x4*)(linb + g * 4);

    long ngroups = (Nd + 15) >> 4;
    for (long it = blockIdx.x; it < ngroups; it += gridDim.x) {
        int d = (int)(it * 16) + grp;
        if (d >= Nd) continue;
        const short* grow = (const short*)gr + (size_t)d * 256 + eoff;
        short8 gr0 = *(const short8*)grow;
        short8 gr1 = *(const short8*)(grow + 8);
        float grf[16];
        cvt16(gr0, gr1, grf);

        unsigned beg = rp[d], end = rp[d + 1];
        float den = 0.f;
        float acc[16];
#pragma unroll
        for (int j = 0; j < 16; ++j) acc[j] = 0.f;

        for (unsigned e = beg; e < end; ++e) {
            int si = ssrc[e];
            const short* glrow = (const short*)gl + (size_t)si * 256 + eoff;
            short8 gA = *(const short8*)glrow;
            short8 gB = *(const short8*)(glrow + 8);
            float glf[16];
            cvt16(gA, gB, glf);
            float pd = 0.f;
#pragma unroll
            for (int j = 0; j < 16; ++j) {
                float v = glf[j] + grf[j];
                float lr = fmaxf(v, 0.2f * v);
                pd = fmaf(lr, at[j], pd);
            }
            pd = dppadd<DPP_RR4>(pd);     // sum over stride-4 lanes (same head)
            pd = dppadd<DPP_RR8>(pd);
            float w = __expf(pd);
            den += w;
#pragma unroll
            for (int j = 0; j < 16; ++j) acc[j] = fmaf(w, glf[j], acc[j]);
        }
        float inv = den > 0.f ? 1.f / den : 0.f;

        float x[16];
#pragma unroll
        for (int j = 0; j < 16; ++j) {
            float v = acc[j] * inv;
            v = dppadd<DPP_QX1>(v);       // sum over 4 heads (quad)
            v = dppadd<DPP_QX2>(v);
            x[j] = v;
        }
#pragma unroll
        for (int j = 0; j < 16; ++j) {
            float v = fmaf(0.25f, x[j], bL[q * 16 + j]);
            x[j] = v > 0.f ? v : (__expf(v) - 1.f);
        }
        if (h == 0) {
#pragma unroll
            for (int j = 0; j < 16; ++j) hL[grp][q * 16 + j] = x[j];
        }
        __builtin_amdgcn_wave_barrier();   // same-wave LDS producer/consumer

        float y0 = lbv[0], y1 = lbv[1], y2 = lbv[2], y3 = lbv[3];
#pragma unroll
        for (int c = 0; c < 64; c += 4) {
            f32x4 hv = *(const f32x4*)&hL[grp][c];          // broadcast
            const float* wr = WL + c * 64 + g * 4;
            f32x4 w0 = *(const f32x4*)(wr);
            f32x4 w1 = *(const f32x4*)(wr + 64);
            f32x4 w2 = *(const f32x4*)(wr + 128);
            f32x4 w3 = *(const f32x4*)(wr + 192);
            y0 = fmaf(hv[0], w0[0], y0); y1 = fmaf(hv[0], w0[1], y1);
            y2 = fmaf(hv[0], w0[2], y2); y3 = fmaf(hv[0], w0[3], y3);
            y0 = fmaf(hv[1], w1[0], y0); y1 = fmaf(hv[1], w1[1], y1);
            y2 = fmaf(hv[1], w1[2], y2); y3 = fmaf(hv[1], w1[3], y3);
            y0 = fmaf(hv[2], w2[0], y0); y1 = fmaf(hv[2], w2[1], y1);
            y2 = fmaf(hv[2], w2[2], y2); y3 = fmaf(hv[2], w2[3], y3);
            y0 = fmaf(hv[3], w3[0], y0); y1 = fmaf(hv[3], w3[1], y1);
            y2 = fmaf(hv[3], w3[2], y2); y3 = fmaf(hv[3], w3[3], y3);
        }
        float ss = y0 * y0 + y1 * y1 + y2 * y2 + y3 * y3;
        ss = dppadd<DPP_QX1>(ss);
        ss = dppadd<DPP_QX2>(ss);
        ss = dppadd<DPP_RR4>(ss);
        ss = dppadd<DPP_RR8>(ss);
        float rn = 1.f / fmaxf(sqrtf(ss), 1e-12f);
        f32x4 yo = {y0 * rn, y1 * rn, y2 * rn, y3 * rn};
        *(f32x4*)(outp + (size_t)d * 64 + g * 4) = yo;
    }
}

// ---------------------------------------------------------------------------
// gat_b: fused GATv2 (genre phase). One block per dst; 16 lane-groups stride
// edges; no-max softmax => partial merge is a plain sum via LDS.
// Writes h = elu(mean + bias).
// ---------------------------------------------------------------------------
__global__ __launch_bounds__(256) void gat_b(
    const bf16* __restrict__ gl, const bf16* __restrict__ gr,
    const int* __restrict__ ssrc, const unsigned* __restrict__ rp,
    const float* __restrict__ att, const float* __restrict__ bias,
    float* __restrict__ hout, int Nd)
{
    __shared__ float accL[16][256];
    __shared__ float denL[16][4];
    int grp = threadIdx.x >> 4, g = threadIdx.x & 15;
    int h = g & 3, q = g >> 2;
    int eoff = h * 64 + q * 16;
    int d = blockIdx.x;

    float at[16];
#pragma unroll
    for (int j = 0; j < 16; ++j) at[j] = att[eoff + j];

    const short* grow = (const short*)gr + (size_t)d * 256 + eoff;
    short8 gr0 = *(const short8*)grow;
    short8 gr1 = *(const short8*)(grow + 8);
    float grf[16];
    cvt16(gr0, gr1, grf);

    unsigned beg = rp[d], end = rp[d + 1];
    float den = 0.f;
    float acc[16];
#pragma unroll
    for (int j = 0; j < 16; ++j) acc[j] = 0.f;

    for (unsigned e = beg + grp; e < end; e += 16) {
        int si = ssrc[e];
        const short* glrow = (const short*)gl + (size_t)si * 256 + eoff;
        short8 gA = *(const short8*)glrow;
        short8 gB = *(const short8*)(glrow + 8);
        float glf[16];
        cvt16(gA, gB, glf);
        float pd = 0.f;
#pragma unroll
        for (int j = 0; j < 16; ++j) {
            float v = glf[j] + grf[j];
            float lr = fmaxf(v, 0.2f * v);
            pd = fmaf(lr, at[j], pd);
        }
        pd = dppadd<DPP_RR4>(pd);
        pd = dppadd<DPP_RR8>(pd);
        float w = __expf(pd);
        den += w;
#pragma unroll
        for (int j = 0; j < 16; ++j) acc[j] = fmaf(w, glf[j], acc[j]);
    }
#pragma unroll
    for (int j = 0; j < 16; ++j) accL[grp][eoff + j] = acc[j];
    if (q == 0) denL[grp][h] = den;
    __syncthreads();

    int t = threadIdx.x;
    int hh = t >> 6, cc = t & 63;
    float sa = 0.f, sd = 0.f;
#pragma unroll
    for (int k = 0; k < 16; ++k) { sa += accL[k][hh * 64 + cc]; sd += denL[k][hh]; }
    float xv = sd > 0.f ? sa / sd : 0.f;
    __syncthreads();
    accL[0][t] = xv;
    __syncthreads();
    if (t < 64) {
        float m4 = 0.25f * (accL[0][t] + accL[0][64 + t] + accL[0][128 + t] + accL[0][192 + t]);
        float v = m4 + bias[t];
        hout[(size_t)d * 64 + t] = v > 0.f ? v : (__expf(v) - 1.f);
    }
}

// ---------------------------------------------------------------------------
__global__ __launch_bounds__(256) void nrm(
    const float* __restrict__ y, float* __restrict__ norm, int Nn)
{
    int n = blockIdx.x * 256 + threadIdx.x;
    if (n >= Nn) return;
    const float* yp = y + (size_t)n * 64;
    float ss = 0.f;
    for (int j = 0; j < 64; ++j) ss += yp[j] * yp[j];
    norm[n] = fmaxf(sqrtf(ss), 1e-12f);
}

__global__ __launch_bounds__(256) void nout(
    const float* __restrict__ y, const float* __restrict__ norm,
    float* __restrict__ out, long total)
{
    long i = (long)blockIdx.x * 256 + threadIdx.x;
    if (i >= total) return;
    int n = (int)(i >> 6);
    out[i] = y[i] / norm[n];
}

// ---------------------------------------------------------------------------

static inline unsigned gridFor(long n) { return (unsigned)((n + 255) / 256); }

extern "C" void kernel_launch(void* const* d_in, const int* in_sizes, int n_in,
                              void* d_out, int out_size, void* d_ws, size_t ws_size,
                              hipStream_t stream) {
    const float* x_artist = (const float*)d_in[0];
    const float* x_track  = (const float*)d_in[1];
    const float* x_genre  = (const float*)d_in[2];
    const float* enc_Wa = (const float*)d_in[3];  const float* enc_ba = (const float*)d_in[4];
    const float* enc_Wt = (const float*)d_in[5];  const float* enc_bt = (const float*)d_in[6];
    const float* enc_Wg = (const float*)d_in[7];  const float* enc_bg = (const float*)d_in[8];
    const int* src_pt = (const int*)d_in[9];
    const int* dst_pt = (const int*)d_in[10];
    const int* src_tg = (const int*)d_in[11];
    const int* dst_tg = (const int*)d_in[12];
    // layer l=1 slices (hidden never fed back -> only last layer matters)
    const float* Wl_pt   = (const float*)d_in[13] + 64 * 256;
    const float* bl_pt   = (const float*)d_in[14] + 256;
    const float* Wr_pt   = (const float*)d_in[15] + 64 * 256;
    const float* br_pt   = (const float*)d_in[16] + 256;
    const float* att_pt  = (const float*)d_in[17] + 256;
    const float* bias_pt = (const float*)d_in[18] + 64;
    const float* Wl_tg   = (const float*)d_in[19] + 64 * 256;
    const float* bl_tg   = (const float*)d_in[20] + 256;
    const float* Wr_tg   = (const float*)d_in[21] + 64 * 256;
    const float* br_tg   = (const float*)d_in[22] + 256;
    const float* att_tg  = (const float*)d_in[23] + 256;
    const float* bias_tg = (const float*)d_in[24] + 64;
    const float* lin_track_W = (const float*)d_in[25];
    const float* lin_track_b = (const float*)d_in[26];
    const float* lin_genre_W = (const float*)d_in[27];
    const float* lin_genre_b = (const float*)d_in[28];

    float* out = (float*)d_out;

    // ---- workspace layout (~264 MB) ----
    char* p = (char*)d_ws;
    auto take = [&](size_t bytes) { char* q = p; p += (bytes + 255) & ~(size_t)255; return q; };
    bf16* enc_t = (bf16*)take((size_t)NT * 64 * 2);
    bf16* enc_g = (bf16*)take((size_t)NG * 64 * 2);
    bf16* enc_a = (bf16*)take((size_t)NA * 64 * 2);        // tg phase: gr_tg overlays
    char* region = take((size_t)NA * 256 * 2 + (size_t)NT * 256 * 2);   // 204.8 MB
    bf16*  gl_pt  = (bf16*)region;                                      // pt: [0, 51.2 MB)
    bf16*  gr_pt  = (bf16*)(region + (size_t)NA * 256 * 2);             // pt: [51.2, 204.8)
    bf16*  gl_tg  = (bf16*)region;                                      // tg: [0, 153.6)
    float* hsum_g = (float*)(region + (size_t)NT * 256 * 2);            // tg: +0.5 MB
    float* ybuf_g = hsum_g + (size_t)NG * 64;
    bf16*  gr_tg  = (bf16*)enc_a;                                       // NG*256 fits
    unsigned* counts = (unsigned*)take((size_t)(NT + 1) * 4);
    unsigned* rowptr = (unsigned*)take((size_t)(NT + 1) * 4);
    unsigned* cursor = (unsigned*)take((size_t)NT * 4);
    unsigned* part   = (unsigned*)take((size_t)2048 * 4);
    int*      ssrc   = (int*)take((size_t)EPT * 4);
    short*    Bf     = (short*)take((size_t)4 * 16384 * 2);
    float*    norm   = (float*)take((size_t)NT * 4);

    short* BfA  = Bf;              // Wl_pt frag
    short* BfA2 = Bf + 16384;      // Wr_pt frag
    short* BfB  = Bf + 32768;      // Wl_tg frag
    short* BfB2 = Bf + 49152;      // Wr_tg frag

    dim3 blk(256);

    // ---- weight converts ----
    cvtW<<<8, blk, 0, stream>>>(Wl_pt, BfA);
    cvtW<<<8, blk, 0, stream>>>(Wr_pt, BfA2);
    cvtW<<<8, blk, 0, stream>>>(Wl_tg, BfB);
    cvtW<<<8, blk, 0, stream>>>(Wr_tg, BfB2);

    // ---- sort pt edges by dst (counting sort -> CSR) ----
    {
        int n = NT + 1;
        unsigned sgrid = (unsigned)((n + 1023) / 1024);
        fill_u32<<<gridFor(n), blk, 0, stream>>>(counts, 0u, n);
        histo<<<gridFor(EPT), blk, 0, stream>>>(dst_pt, counts, EPT);
        scan_a<<<sgrid, blk, 0, stream>>>(counts, rowptr, part, n);
        scan_a<<<1, blk, 0, stream>>>(part, part, part + 1536, (int)sgrid);
        scan_c<<<gridFor(n), blk, 0, stream>>>(rowptr, part, cursor, n);
        scat<<<gridFor(EPT), blk, 0, stream>>>(src_pt, dst_pt, cursor, ssrc, EPT);
    }

    // ---- encoders ----
    ngemm_c4<true><<<gridFor((long)NA * 16), blk, 0, stream>>>(x_artist, enc_Wa, enc_ba, enc_a, NA, 64, 64);
    ngemm_c4<true><<<gridFor((long)NT * 16), blk, 0, stream>>>(x_track,  enc_Wt, enc_bt, enc_t, NT, 64, 96);
    ngemm_c4<true><<<gridFor((long)NG * 16), blk, 0, stream>>>(x_genre,  enc_Wg, enc_bg, enc_g, NG, 64, 32);

    // ================= performed: artist -> track =================
    tform<<<(NA + 63) / 64, blk, 0, stream>>>(enc_a, BfA,  bl_pt, gl_pt, NA);
    tform<<<(NT + 63) / 64, blk, 0, stream>>>(enc_t, BfA2, br_pt, gr_pt, NT);

    gat_w<<<2048, blk, 0, stream>>>(gl_pt, gr_pt, ssrc, rowptr, att_pt, bias_pt,
                                    lin_track_W, lin_track_b, out, NT);

    // ---- sort tg edges by dst ----
    {
        int n = NG + 1;
        unsigned sgrid = (unsigned)((n + 1023) / 1024);
        fill_u32<<<gridFor(n), blk, 0, stream>>>(counts, 0u, n);
        histo<<<gridFor(ETG), blk, 0, stream>>>(dst_tg, counts, ETG);
        scan_a<<<sgrid, blk, 0, stream>>>(counts, rowptr, part, n);
        scan_a<<<1, blk, 0, stream>>>(part, part, part + 1536, (int)sgrid);
        scan_c<<<gridFor(n), blk, 0, stream>>>(rowptr, part, cursor, n);
        scat<<<gridFor(ETG), blk, 0, stream>>>(src_tg, dst_tg, cursor, ssrc, ETG);
    }

    // ================= has_genre: track -> genre =================
    tform<<<(NT + 63) / 64, blk, 0, stream>>>(enc_t, BfB,  bl_tg, gl_tg, NT);
    tform<<<(NG + 63) / 64, blk, 0, stream>>>(enc_g, BfB2, br_tg, gr_tg, NG);

    gat_b<<<NG, blk, 0, stream>>>(gl_tg, gr_tg, ssrc, rowptr, att_tg, bias_tg, hsum_g, NG);

    ngemm_c4<false><<<gridFor((long)NG * 16), blk, 0, stream>>>(hsum_g, lin_genre_W, lin_genre_b, ybuf_g, NG, 64, 64);
    nrm <<<gridFor(NG), blk, 0, stream>>>(ybuf_g, norm, NG);
    nout<<<gridFor((long)NG * 64), blk, 0, stream>>>(ybuf_g, norm, out + (size_t)NT * 64, (long)NG * 64);
}

// Round 4
// 876.011 us; speedup vs baseline: 6.1228x; 1.2412x over previous
//
#include <hip/hip_runtime.h>
#include <hip/hip_bf16.h>

typedef __hip_bfloat16 bf16;
typedef __attribute__((ext_vector_type(8))) short short8;   // 8 bf16 (4 VGPRs)
typedef __attribute__((ext_vector_type(4))) float f32x4;

#define NA 100000
#define NT 300000
#define NG 2000
#define EPT 600000
#define ETG 400000

// DPP control codes
#define DPP_QX1 0xB1   // quad_perm [1,0,3,2]  (xor 1)
#define DPP_QX2 0x4E   // quad_perm [2,3,0,1]  (xor 2)
#define DPP_RR4 0x124  // row_ror:4
#define DPP_RR8 0x128  // row_ror:8

template <int CTRL>
__device__ __forceinline__ float dppadd(float x) {
    int y = __builtin_amdgcn_update_dpp(0, __float_as_int(x), CTRL, 0xf, 0xf, true);
    return x + __int_as_float(y);
}

__device__ __forceinline__ float b2f(short s) {
    return __uint_as_float(((unsigned)(unsigned short)s) << 16);
}
__device__ __forceinline__ void cvt16(short8 a, short8 b, float* f) {
#pragma unroll
    for (int j = 0; j < 8; ++j) f[j] = b2f(a[j]);
#pragma unroll
    for (int j = 0; j < 8; ++j) f[8 + j] = b2f(b[j]);
}
__device__ __forceinline__ short f2bs(float x) {
    return (short)__builtin_bit_cast(unsigned short, __float2bfloat16(x));
}

__global__ void fill_u32(unsigned* __restrict__ p, unsigned v, long n) {
    long i = (long)blockIdx.x * 256 + threadIdx.x;
    if (i < n) p[i] = v;
}

// ---------------------------------------------------------------------------
// wcomb: Wc[K x 256] = We[K x 64] @ Wl[64 x 256]   (f32, tiny)
// ---------------------------------------------------------------------------
__global__ __launch_bounds__(256) void wcomb(
    const float* __restrict__ We, const float* __restrict__ Wl,
    float* __restrict__ Wc, int K)
{
    int i = blockIdx.x * 256 + threadIdx.x;
    if (i >= K * 256) return;
    int k = i >> 8, j = i & 255;
    float acc = 0.f;
    for (int c = 0; c < 64; ++c) acc = fmaf(We[k * 64 + c], Wl[c * 256 + j], acc);
    Wc[i] = acc;
}

// bc[256] = be[64] @ Wl[64x256] + bl[256]
__global__ __launch_bounds__(256) void bcomb(
    const float* __restrict__ be, const float* __restrict__ Wl,
    const float* __restrict__ bl, float* __restrict__ bc)
{
    int j = threadIdx.x;
    float acc = bl[j];
    for (int c = 0; c < 64; ++c) acc = fmaf(be[c], Wl[c * 256 + j], acc);
    bc[j] = acc;
}

// ---------------------------------------------------------------------------
// cvtWk: convert a K x 256 f32 weight to bf16 in MFMA B-fragment order.
// idx = (((ks*16+nt)*4 + kb)*16 + c)*8 + j  holds  W[(ks*32+kb*8+j)*256 + nt*16+c]
// KS = K/32 k-steps; KS*1024 threads.
// ---------------------------------------------------------------------------
__global__ __launch_bounds__(256) void cvtWk(
    const float* __restrict__ W, short* __restrict__ Bf, int KS)
{
    int t = blockIdx.x * 256 + threadIdx.x;
    if (t >= KS * 1024) return;
    int c = t & 15, kb = (t >> 4) & 3, nt = (t >> 6) & 15, ks = t >> 10;
    int k0 = ks * 32 + kb * 8, n = nt * 16 + c;
    short8 o;
#pragma unroll
    for (int j = 0; j < 8; ++j) o[j] = f2bs(W[(size_t)(k0 + j) * 256 + n]);
    *((short8*)Bf + t) = o;
}

// ---------------------------------------------------------------------------
// tformf: C[M x 256] = bf16(A[M x K] f32) @ B (bf16 frag-ordered) + bias, MFMA.
// K = KS*32. Encoder folded into B (combined weight). A converted in-register.
// ---------------------------------------------------------------------------
template <int KS>
__global__ __launch_bounds__(256) void tformf(
    const float* __restrict__ A, const short* __restrict__ Bf,
    const float* __restrict__ bias, bf16* __restrict__ C, int M)
{
    constexpr int K = KS * 32;
    int wv = threadIdx.x >> 6, lane = threadIdx.x & 63;
    int lrow = lane & 15, kb = lane >> 4;
    int base = blockIdx.x * 64 + wv * 16;

    int arow = base + lrow; if (arow >= M) arow = M - 1;
    const float* Ap = A + (size_t)arow * K + kb * 8;
    short8 a[KS];
#pragma unroll
    for (int s = 0; s < KS; ++s) {
        f32x4 lo = *(const f32x4*)(Ap + s * 32);
        f32x4 hi = *(const f32x4*)(Ap + s * 32 + 4);
#pragma unroll
        for (int j = 0; j < 4; ++j) {
            a[s][j]     = f2bs(lo[j]);
            a[s][4 + j] = f2bs(hi[j]);
        }
    }

    const short8* Bl = (const short8*)Bf + kb * 16 + lrow;

    f32x4 acc[16];
#pragma unroll
    for (int nt = 0; nt < 16; ++nt) {
        float bv = bias[nt * 16 + lrow];
        f32x4 bvv = {bv, bv, bv, bv};
        acc[nt] = bvv;
    }
#pragma unroll
    for (int nt = 0; nt < 16; ++nt) {
#pragma unroll
        for (int s = 0; s < KS; ++s)
            acc[nt] = __builtin_amdgcn_mfma_f32_16x16x32_bf16(
                a[s], Bl[(s * 16 + nt) * 64], acc[nt], 0, 0, 0);
    }
    int r0 = base + kb * 4;
#pragma unroll
    for (int nt = 0; nt < 16; ++nt) {
#pragma unroll
        for (int r = 0; r < 4; ++r) {
            int row = r0 + r;
            if (row < M)
                C[(size_t)row * 256 + nt * 16 + lrow] = __float2bfloat16(acc[nt][r]);
        }
    }
}

// ---------------------------------------------------------------------------
// ngemm_c4: f32 GEMM, thread per 4 cols (genre-tail only; tiny M).
// ---------------------------------------------------------------------------
__global__ __launch_bounds__(256) void ngemm_c4(
    const float* __restrict__ A, const float* __restrict__ B,
    const float* __restrict__ bias, float* __restrict__ C,
    int M, int N, int K)
{
    long i = (long)blockIdx.x * 256 + threadIdx.x;
    int nq = N >> 2;
    if (i >= (long)M * nq) return;
    int n = (int)(i / nq);
    int c4 = (int)(i - (long)n * nq) << 2;
    const float* Ap = A + (size_t)n * K;
    f32x4 acc = *(const f32x4*)(bias + c4);
    for (int k = 0; k < K; k += 4) {
        f32x4 a = *(const f32x4*)(Ap + k);
#pragma unroll
        for (int kk = 0; kk < 4; ++kk) {
            f32x4 b = *(const f32x4*)(B + (size_t)(k + kk) * N + c4);
            acc += a[kk] * b;
        }
    }
    *(f32x4*)(C + (size_t)n * N + c4) = acc;
}

// ============================ edge sort (CSR by dst) ========================
__global__ __launch_bounds__(256) void histo(
    const int* __restrict__ dst, unsigned* __restrict__ cnt, int E)
{
    int i = blockIdx.x * 256 + threadIdx.x;
    if (i < E) atomicAdd(&cnt[dst[i]], 1u);
}

__global__ __launch_bounds__(256) void scan_a(
    const unsigned* __restrict__ in, unsigned* __restrict__ out,
    unsigned* __restrict__ part, int n)
{
    __shared__ unsigned ts[256];
    int t = threadIdx.x;
    long base = (long)blockIdx.x * 1024 + (long)t * 4;
    unsigned v0 = 0, v1 = 0, v2 = 0, v3 = 0;
    if (base + 0 < n) v0 = in[base + 0];
    if (base + 1 < n) v1 = in[base + 1];
    if (base + 2 < n) v2 = in[base + 2];
    if (base + 3 < n) v3 = in[base + 3];
    unsigned s = v0 + v1 + v2 + v3;
    ts[t] = s;
    __syncthreads();
    unsigned run = s;
    for (int off = 1; off < 256; off <<= 1) {
        unsigned y = (t >= off) ? ts[t - off] : 0u;
        __syncthreads();
        run += y; ts[t] = run;
        __syncthreads();
    }
    unsigned ex = run - s;
    if (base + 0 < n) out[base + 0] = ex;
    if (base + 1 < n) out[base + 1] = ex + v0;
    if (base + 2 < n) out[base + 2] = ex + v0 + v1;
    if (base + 3 < n) out[base + 3] = ex + v0 + v1 + v2;
    if (t == 255) part[blockIdx.x] = run;
}

__global__ __launch_bounds__(256) void scan_c(
    unsigned* __restrict__ rp, const unsigned* __restrict__ part,
    unsigned* __restrict__ cur, int n)
{
    long i = (long)blockIdx.x * 256 + threadIdx.x;
    if (i >= n) return;
    unsigned v = rp[i] + part[i >> 10];
    rp[i] = v;
    if (i < n - 1) cur[i] = v;
}

__global__ __launch_bounds__(256) void scat(
    const int* __restrict__ src, const int* __restrict__ dst,
    unsigned* __restrict__ cur, int* __restrict__ ss, int E)
{
    int i = blockIdx.x * 256 + threadIdx.x;
    if (i < E) {
        unsigned p = atomicAdd(&cur[dst[i]], 1u);
        ss[p] = src[i];
    }
}

// ---------------------------------------------------------------------------
// gat_w: fused GATv2 (track phase), 16-lane-group per dst (4 dst per wave).
// No running max (|logit| << 1); DPP reduces; epilogue fuses
// bias+elu+64x64 linear+l2norm+store.
// ---------------------------------------------------------------------------
__global__ __launch_bounds__(256) void gat_w(
    const bf16* __restrict__ gl, const bf16* __restrict__ gr,
    const int* __restrict__ ssrc, const unsigned* __restrict__ rp,
    const float* __restrict__ att, const float* __restrict__ bias,
    const float* __restrict__ linW, const float* __restrict__ linb,
    float* __restrict__ outp, int Nd)
{
    __shared__ float WL[4096];        // linW [c][j] row-major
    __shared__ float bL[64];
    __shared__ float hL[16][68];      // per-group h, padded
    for (int t = threadIdx.x; t < 4096; t += 256) WL[t] = linW[t];
    if (threadIdx.x < 64) bL[threadIdx.x] = bias[threadIdx.x];
    __syncthreads();

    int grp = threadIdx.x >> 4, g = threadIdx.x & 15;
    int h = g & 3, q = g >> 2;
    int eoff = h * 64 + q * 16;

    float at[16];
#pragma unroll
    for (int j = 0; j < 16; ++j) at[j] = att[eoff + j];
    f32x4 lbv = *(const f32x4*)(linb + g * 4);

    long ngroups = (Nd + 15) >> 4;
    for (long it = blockIdx.x; it < ngroups; it += gridDim.x) {
        int d = (int)(it * 16) + grp;
        if (d >= Nd) continue;
        const short* grow = (const short*)gr + (size_t)d * 256 + eoff;
        short8 gr0 = *(const short8*)grow;
        short8 gr1 = *(const short8*)(grow + 8);
        float grf[16];
        cvt16(gr0, gr1, grf);

        unsigned beg = rp[d], end = rp[d + 1];
        float den = 0.f;
        float acc[16];
#pragma unroll
        for (int j = 0; j < 16; ++j) acc[j] = 0.f;

        for (unsigned e = beg; e < end; ++e) {
            int si = ssrc[e];
            const short* glrow = (const short*)gl + (size_t)si * 256 + eoff;
            short8 gA = *(const short8*)glrow;
            short8 gB = *(const short8*)(glrow + 8);
            float glf[16];
            cvt16(gA, gB, glf);
            float pd = 0.f;
#pragma unroll
            for (int j = 0; j < 16; ++j) {
                float v = glf[j] + grf[j];
                float lr = fmaxf(v, 0.2f * v);
                pd = fmaf(lr, at[j], pd);
            }
            pd = dppadd<DPP_RR4>(pd);     // sum over stride-4 lanes (same head)
            pd = dppadd<DPP_RR8>(pd);
            float w = __expf(pd);
            den += w;
#pragma unroll
            for (int j = 0; j < 16; ++j) acc[j] = fmaf(w, glf[j], acc[j]);
        }
        float inv = den > 0.f ? 1.f / den : 0.f;

        float x[16];
#pragma unroll
        for (int j = 0; j < 16; ++j) {
            float v = acc[j] * inv;
            v = dppadd<DPP_QX1>(v);       // sum over 4 heads (quad)
            v = dppadd<DPP_QX2>(v);
            x[j] = v;
        }
#pragma unroll
        for (int j = 0; j < 16; ++j) {
            float v = fmaf(0.25f, x[j], bL[q * 16 + j]);
            x[j] = v > 0.f ? v : (__expf(v) - 1.f);
        }
        if (h == 0) {
#pragma unroll
            for (int j = 0; j < 16; ++j) hL[grp][q * 16 + j] = x[j];
        }
        __builtin_amdgcn_wave_barrier();   // same-wave LDS producer/consumer

        float y0 = lbv[0], y1 = lbv[1], y2 = lbv[2], y3 = lbv[3];
#pragma unroll
        for (int c = 0; c < 64; c += 4) {
            f32x4 hv = *(const f32x4*)&hL[grp][c];          // broadcast
            const float* wr = WL + c * 64 + g * 4;
            f32x4 w0 = *(const f32x4*)(wr);
            f32x4 w1 = *(const f32x4*)(wr + 64);
            f32x4 w2 = *(const f32x4*)(wr + 128);
            f32x4 w3 = *(const f32x4*)(wr + 192);
            y0 = fmaf(hv[0], w0[0], y0); y1 = fmaf(hv[0], w0[1], y1);
            y2 = fmaf(hv[0], w0[2], y2); y3 = fmaf(hv[0], w0[3], y3);
            y0 = fmaf(hv[1], w1[0], y0); y1 = fmaf(hv[1], w1[1], y1);
            y2 = fmaf(hv[1], w1[2], y2); y3 = fmaf(hv[1], w1[3], y3);
            y0 = fmaf(hv[2], w2[0], y0); y1 = fmaf(hv[2], w2[1], y1);
            y2 = fmaf(hv[2], w2[2], y2); y3 = fmaf(hv[2], w2[3], y3);
            y0 = fmaf(hv[3], w3[0], y0); y1 = fmaf(hv[3], w3[1], y1);
            y2 = fmaf(hv[3], w3[2], y2); y3 = fmaf(hv[3], w3[3], y3);
        }
        float ss = y0 * y0 + y1 * y1 + y2 * y2 + y3 * y3;
        ss = dppadd<DPP_QX1>(ss);
        ss = dppadd<DPP_QX2>(ss);
        ss = dppadd<DPP_RR4>(ss);
        ss = dppadd<DPP_RR8>(ss);
        float rn = 1.f / fmaxf(sqrtf(ss), 1e-12f);
        f32x4 yo = {y0 * rn, y1 * rn, y2 * rn, y3 * rn};
        *(f32x4*)(outp + (size_t)d * 64 + g * 4) = yo;
    }
}

// ---------------------------------------------------------------------------
// gat_b: fused GATv2 (genre phase). One block per dst; 16 lane-groups stride
// edges; no-max softmax => partial merge is a plain sum via LDS.
// ---------------------------------------------------------------------------
__global__ __launch_bounds__(256) void gat_b(
    const bf16* __restrict__ gl, const bf16* __restrict__ gr,
    const int* __restrict__ ssrc, const unsigned* __restrict__ rp,
    const float* __restrict__ att, const float* __restrict__ bias,
    float* __restrict__ hout, int Nd)
{
    __shared__ float accL[16][256];
    __shared__ float denL[16][4];
    int grp = threadIdx.x >> 4, g = threadIdx.x & 15;
    int h = g & 3, q = g >> 2;
    int eoff = h * 64 + q * 16;
    int d = blockIdx.x;

    float at[16];
#pragma unroll
    for (int j = 0; j < 16; ++j) at[j] = att[eoff + j];

    const short* grow = (const short*)gr + (size_t)d * 256 + eoff;
    short8 gr0 = *(const short8*)grow;
    short8 gr1 = *(const short8*)(grow + 8);
    float grf[16];
    cvt16(gr0, gr1, grf);

    unsigned beg = rp[d], end = rp[d + 1];
    float den = 0.f;
    float acc[16];
#pragma unroll
    for (int j = 0; j < 16; ++j) acc[j] = 0.f;

    for (unsigned e = beg + grp; e < end; e += 16) {
        int si = ssrc[e];
        const short* glrow = (const short*)gl + (size_t)si * 256 + eoff;
        short8 gA = *(const short8*)glrow;
        short8 gB = *(const short8*)(glrow + 8);
        float glf[16];
        cvt16(gA, gB, glf);
        float pd = 0.f;
#pragma unroll
        for (int j = 0; j < 16; ++j) {
            float v = glf[j] + grf[j];
            float lr = fmaxf(v, 0.2f * v);
            pd = fmaf(lr, at[j], pd);
        }
        pd = dppadd<DPP_RR4>(pd);
        pd = dppadd<DPP_RR8>(pd);
        float w = __expf(pd);
        den += w;
#pragma unroll
        for (int j = 0; j < 16; ++j) acc[j] = fmaf(w, glf[j], acc[j]);
    }
#pragma unroll
    for (int j = 0; j < 16; ++j) accL[grp][eoff + j] = acc[j];
    if (q == 0) denL[grp][h] = den;
    __syncthreads();

    int t = threadIdx.x;
    int hh = t >> 6, cc = t & 63;
    float sa = 0.f, sd = 0.f;
#pragma unroll
    for (int k = 0; k < 16; ++k) { sa += accL[k][hh * 64 + cc]; sd += denL[k][hh]; }
    float xv = sd > 0.f ? sa / sd : 0.f;
    __syncthreads();
    accL[0][t] = xv;
    __syncthreads();
    if (t < 64) {
        float m4 = 0.25f * (accL[0][t] + accL[0][64 + t] + accL[0][128 + t] + accL[0][192 + t]);
        float v = m4 + bias[t];
        hout[(size_t)d * 64 + t] = v > 0.f ? v : (__expf(v) - 1.f);
    }
}

// ---------------------------------------------------------------------------
__global__ __launch_bounds__(256) void nrm(
    const float* __restrict__ y, float* __restrict__ norm, int Nn)
{
    int n = blockIdx.x * 256 + threadIdx.x;
    if (n >= Nn) return;
    const float* yp = y + (size_t)n * 64;
    float ss = 0.f;
    for (int j = 0; j < 64; ++j) ss += yp[j] * yp[j];
    norm[n] = fmaxf(sqrtf(ss), 1e-12f);
}

__global__ __launch_bounds__(256) void nout(
    const float* __restrict__ y, const float* __restrict__ norm,
    float* __restrict__ out, long total)
{
    long i = (long)blockIdx.x * 256 + threadIdx.x;
    if (i >= total) return;
    int n = (int)(i >> 6);
    out[i] = y[i] / norm[n];
}

// ---------------------------------------------------------------------------

static inline unsigned gridFor(long n) { return (unsigned)((n + 255) / 256); }

extern "C" void kernel_launch(void* const* d_in, const int* in_sizes, int n_in,
                              void* d_out, int out_size, void* d_ws, size_t ws_size,
                              hipStream_t stream) {
    const float* x_artist = (const float*)d_in[0];
    const float* x_track  = (const float*)d_in[1];
    const float* x_genre  = (const float*)d_in[2];
    const float* enc_Wa = (const float*)d_in[3];  const float* enc_ba = (const float*)d_in[4];
    const float* enc_Wt = (const float*)d_in[5];  const float* enc_bt = (const float*)d_in[6];
    const float* enc_Wg = (const float*)d_in[7];  const float* enc_bg = (const float*)d_in[8];
    const int* src_pt = (const int*)d_in[9];
    const int* dst_pt = (const int*)d_in[10];
    const int* src_tg = (const int*)d_in[11];
    const int* dst_tg = (const int*)d_in[12];
    // layer l=1 slices (hidden never fed back -> only last layer matters)
    const float* Wl_pt   = (const float*)d_in[13] + 64 * 256;
    const float* bl_pt   = (const float*)d_in[14] + 256;
    const float* Wr_pt   = (const float*)d_in[15] + 64 * 256;
    const float* br_pt   = (const float*)d_in[16] + 256;
    const float* att_pt  = (const float*)d_in[17] + 256;
    const float* bias_pt = (const float*)d_in[18] + 64;
    const float* Wl_tg   = (const float*)d_in[19] + 64 * 256;
    const float* bl_tg   = (const float*)d_in[20] + 256;
    const float* Wr_tg   = (const float*)d_in[21] + 64 * 256;
    const float* br_tg   = (const float*)d_in[22] + 256;
    const float* att_tg  = (const float*)d_in[23] + 256;
    const float* bias_tg = (const float*)d_in[24] + 64;
    const float* lin_track_W = (const float*)d_in[25];
    const float* lin_track_b = (const float*)d_in[26];
    const float* lin_genre_W = (const float*)d_in[27];
    const float* lin_genre_b = (const float*)d_in[28];

    float* out = (float*)d_out;

    // ---- workspace layout (~215 MB) ----
    char* p = (char*)d_ws;
    auto take = [&](size_t bytes) { char* q = p; p += (bytes + 255) & ~(size_t)255; return q; };
    char* region = take((size_t)NA * 256 * 2 + (size_t)NT * 256 * 2);   // 204.8 MB
    bf16*  gl_pt  = (bf16*)region;                                      // pt: [0, 51.2 MB)
    bf16*  gr_pt  = (bf16*)(region + (size_t)NA * 256 * 2);             // pt: [51.2, 204.8)
    bf16*  gl_tg  = (bf16*)region;                                      // tg: [0, 153.6)
    float* hsum_g = (float*)(region + (size_t)NT * 256 * 2);            // tg: +0.5 MB
    float* ybuf_g = hsum_g + (size_t)NG * 64;
    unsigned* counts = (unsigned*)take((size_t)(NT + 1) * 4);
    unsigned* rowptr = (unsigned*)take((size_t)(NT + 1) * 4);
    unsigned* cursor = (unsigned*)take((size_t)NT * 4);
    unsigned* part   = (unsigned*)take((size_t)2048 * 4);
    int*      ssrc   = (int*)take((size_t)EPT * 4);
    bf16*     gr_tg  = (bf16*)take((size_t)NG * 256 * 2);               // 1 MB
    float*    Wcf    = (float*)take((size_t)96 * 256 * 4);              // f32 combined tmp
    short*    Bf     = (short*)take((size_t)(64 + 96 + 96 + 32) * 256 * 2);
    float*    bc     = (float*)take((size_t)4 * 256 * 4);
    float*    norm   = (float*)take((size_t)NT * 4);

    short* BfGLpt = Bf;                       // K=64
    short* BfGRpt = BfGLpt + 64 * 256;        // K=96
    short* BfGLtg = BfGRpt + 96 * 256;        // K=96
    short* BfGRtg = BfGLtg + 96 * 256;        // K=32
    float* bcGLpt = bc;
    float* bcGRpt = bc + 256;
    float* bcGLtg = bc + 512;
    float* bcGRtg = bc + 768;

    dim3 blk(256);

    // ---- fold encoders into GAT transforms: Wc = We@W*, bc = be@W* + b* ----
    wcomb<<<gridFor(64 * 256), blk, 0, stream>>>(enc_Wa, Wl_pt, Wcf, 64);
    cvtWk<<<8,  blk, 0, stream>>>(Wcf, BfGLpt, 2);
    bcomb<<<1, blk, 0, stream>>>(enc_ba, Wl_pt, bl_pt, bcGLpt);

    wcomb<<<gridFor(96 * 256), blk, 0, stream>>>(enc_Wt, Wr_pt, Wcf, 96);
    cvtWk<<<12, blk, 0, stream>>>(Wcf, BfGRpt, 3);
    bcomb<<<1, blk, 0, stream>>>(enc_bt, Wr_pt, br_pt, bcGRpt);

    wcomb<<<gridFor(96 * 256), blk, 0, stream>>>(enc_Wt, Wl_tg, Wcf, 96);
    cvtWk<<<12, blk, 0, stream>>>(Wcf, BfGLtg, 3);
    bcomb<<<1, blk, 0, stream>>>(enc_bt, Wl_tg, bl_tg, bcGLtg);

    wcomb<<<gridFor(32 * 256), blk, 0, stream>>>(enc_Wg, Wr_tg, Wcf, 32);
    cvtWk<<<4,  blk, 0, stream>>>(Wcf, BfGRtg, 1);
    bcomb<<<1, blk, 0, stream>>>(enc_bg, Wr_tg, br_tg, bcGRtg);

    // ---- sort pt edges by dst (counting sort -> CSR) ----
    {
        int n = NT + 1;
        unsigned sgrid = (unsigned)((n + 1023) / 1024);
        fill_u32<<<gridFor(n), blk, 0, stream>>>(counts, 0u, n);
        histo<<<gridFor(EPT), blk, 0, stream>>>(dst_pt, counts, EPT);
        scan_a<<<sgrid, blk, 0, stream>>>(counts, rowptr, part, n);
        scan_a<<<1, blk, 0, stream>>>(part, part, part + 1536, (int)sgrid);
        scan_c<<<gridFor(n), blk, 0, stream>>>(rowptr, part, cursor, n);
        scat<<<gridFor(EPT), blk, 0, stream>>>(src_pt, dst_pt, cursor, ssrc, EPT);
    }

    // ================= performed: artist -> track =================
    tformf<2><<<(NA + 63) / 64, blk, 0, stream>>>(x_artist, BfGLpt, bcGLpt, gl_pt, NA);
    tformf<3><<<(NT + 63) / 64, blk, 0, stream>>>(x_track,  BfGRpt, bcGRpt, gr_pt, NT);

    gat_w<<<2048, blk, 0, stream>>>(gl_pt, gr_pt, ssrc, rowptr, att_pt, bias_pt,
                                    lin_track_W, lin_track_b, out, NT);

    // ---- sort tg edges by dst ----
    {
        int n = NG + 1;
        unsigned sgrid = (unsigned)((n + 1023) / 1024);
        fill_u32<<<gridFor(n), blk, 0, stream>>>(counts, 0u, n);
        histo<<<gridFor(ETG), blk, 0, stream>>>(dst_tg, counts, ETG);
        scan_a<<<sgrid, blk, 0, stream>>>(counts, rowptr, part, n);
        scan_a<<<1, blk, 0, stream>>>(part, part, part + 1536, (int)sgrid);
        scan_c<<<gridFor(n), blk, 0, stream>>>(rowptr, part, cursor, n);
        scat<<<gridFor(ETG), blk, 0, stream>>>(src_tg, dst_tg, cursor, ssrc, ETG);
    }

    // ================= has_genre: track -> genre =================
    tformf<3><<<(NT + 63) / 64, blk, 0, stream>>>(x_track, BfGLtg, bcGLtg, gl_tg, NT);
    tformf<1><<<(NG + 63) / 64, blk, 0, stream>>>(x_genre, BfGRtg, bcGRtg, gr_tg, NG);

    gat_b<<<NG, blk, 0, stream>>>(gl_tg, gr_tg, ssrc, rowptr, att_tg, bias_tg, hsum_g, NG);

    ngemm_c4<<<gridFor((long)NG * 16), blk, 0, stream>>>(hsum_g, lin_genre_W, lin_genre_b, ybuf_g, NG, 64, 64);
    nrm <<<gridFor(NG), blk, 0, stream>>>(ybuf_g, norm, NG);
    nout<<<gridFor((long)NG * 64), blk, 0, stream>>>(ybuf_g, norm, out + (size_t)NT * 64, (long)NG * 64);
}